// Round 10
// baseline (850.395 us; speedup 1.0000x reference)
//
#include <hip/hip_runtime.h>
#include <hip/hip_fp16.h>

#define Rtot 65536
#define Wimg 256
#define Kp 64
#define NSTEPS 64
#define DTc (1.0f/256.0f)
#define INV_VOLR (1.0f/256.0f)

// ws layout (bytes): pd (4 KB) + packed fp16 template (2 MB)
#define PD_OFF 0u
#define TT_OFF 65536u
#define WS_NEED (TT_OFF + (size_t)Kp*4096*8)

__device__ __forceinline__ unsigned int pack2(float a, float b) {
  __half2 h = __floats2half2_rn(a, b);
  return *(unsigned int*)&h;
}

// Setup: blocks 0..63 repack prim k's template (4,16,16,16) f32 ->
// 4096 x ull of 4 fp16 {c0,c1,c2,c3} (8 B/voxel, 2 MB total);
// block 64 builds prim data (pos_n, rsc[i][j]=rot[i][j]*scale[j]).
__global__ __launch_bounds__(256) void setup_kernel(
    const float* __restrict__ primpos, const float* __restrict__ primrot,
    const float* __restrict__ primscale, const float* __restrict__ tmpl,
    unsigned long long* __restrict__ tth, float* __restrict__ pd) {
  int bid = blockIdx.x, tid = threadIdx.x;
  if (bid < Kp) {
    const float* b0 = tmpl + (((size_t)bid) << 14);
    unsigned long long* o = tth + (bid << 12);
#pragma unroll
    for (int s = 0; s < 16; ++s) {
      int v = s*256 + tid;
      unsigned long long lo = pack2(b0[v],      b0[4096+v]);
      unsigned long long hi = pack2(b0[8192+v], b0[12288+v]);
      o[v] = lo | (hi << 32);
    }
  } else {
    int k = tid;
    if (k < Kp) {
      float sc0 = primscale[k*3+0], sc1 = primscale[k*3+1], sc2 = primscale[k*3+2];
      float* o = pd + (k << 4);
      o[0] = primpos[k*3+0] * INV_VOLR;
      o[1] = primpos[k*3+1] * INV_VOLR;
      o[2] = primpos[k*3+2] * INV_VOLR;
      o[3] = 0.0f; o[4] = 0.0f; o[5] = 0.0f;
#pragma unroll
      for (int i = 0; i < 3; ++i) {
        o[6+i*3+0] = primrot[k*9+i*3+0]*sc0;
        o[6+i*3+1] = primrot[k*9+i*3+1]*sc1;
        o[6+i*3+2] = primrot[k*9+i*3+2]*sc2;
      }
      o[15] = 0.0f;
    }
  }
}

// March: one wave (64 threads) per 8x8-ray quadrant. Inline cull of the 64
// prims vs the quad's full-segment bbox; per surviving prim each ray computes
// its inside t-INTERVAL (local coords are linear in t) and walks only those
// steps, gathering 8x8B voxels and accumulating fp16x4 into a 32KB LDS
// step-buffer; then composites all 64 steps in-register and stores.
__global__ __launch_bounds__(64) void march_kernel(
    const float* __restrict__ raypos, const float* __restrict__ raydir,
    const float* __restrict__ tminmax, const float* __restrict__ pd,
    const unsigned long long* __restrict__ tv, float* __restrict__ out) {
  __shared__ int s_list[Kp];
  __shared__ unsigned long long acc[NSTEPS][64];   // 32 KB
  int b = blockIdx.x;
  int tile = b >> 2, quad = b & 3;
  int lane = threadIdx.x;
  int w = (tile & 15)*16 + (quad & 1)*8 + (lane & 7);
  int h = (tile >> 4)*16 + (quad >> 1)*8 + (lane >> 3);
  int r = h*Wimg + w;
  float ox = raypos[r*3+0], oy = raypos[r*3+1], oz = raypos[r*3+2];
  float dx = raydir[r*3+0], dy = raydir[r*3+1], dz = raydir[r*3+2];
  float tmin = tminmax[r*2+0], tmax = tminmax[r*2+1];

  // bbox of this quad's sampled segment (endpoints; linear in t)
  float tA = tmin + 0.5f*DTc, tB = tmin + ((float)NSTEPS - 0.5f)*DTc;
  float e0x = fmaf(tA, dx, ox), e0y = fmaf(tA, dy, oy), e0z = fmaf(tA, dz, oz);
  float e1x = fmaf(tB, dx, ox), e1y = fmaf(tB, dy, oy), e1z = fmaf(tB, dz, oz);
  float mnx = fminf(e0x, e1x), mxx = fmaxf(e0x, e1x);
  float mny = fminf(e0y, e1y), mxy = fmaxf(e0y, e1y);
  float mnz = fminf(e0z, e1z), mxz = fmaxf(e0z, e1z);
#pragma unroll
  for (int m = 1; m < 64; m <<= 1) {
    mnx = fminf(mnx, __shfl_xor(mnx, m));  mxx = fmaxf(mxx, __shfl_xor(mxx, m));
    mny = fminf(mny, __shfl_xor(mny, m));  mxy = fmaxf(mxy, __shfl_xor(mxy, m));
    mnz = fminf(mnz, __shfl_xor(mnz, m));  mxz = fmaxf(mxz, __shfl_xor(mxz, m));
  }
  // cull: lane tests prim==lane in prim-local space (interval arithmetic)
  {
    const float* p = pd + (lane << 4);
    float rlo0 = mnx - p[0], rhi0 = mxx - p[0];
    float rlo1 = mny - p[1], rhi1 = mxy - p[1];
    float rlo2 = mnz - p[2], rhi2 = mxz - p[2];
    bool pass = true;
#pragma unroll
    for (int j = 0; j < 3; ++j) {
      float a0 = p[6+j], a1 = p[9+j], a2 = p[12+j];
      float q1 = rlo0*a0, q2 = rhi0*a0;
      float llo = fminf(q1, q2), lhi = fmaxf(q1, q2);
      q1 = rlo1*a1; q2 = rhi1*a1;
      llo += fminf(q1, q2); lhi += fmaxf(q1, q2);
      q1 = rlo2*a2; q2 = rhi2*a2;
      llo += fminf(q1, q2); lhi += fmaxf(q1, q2);
      pass = pass && (llo < 1.0f) && (lhi > -1.0f);
    }
    unsigned long long mask = __ballot(pass);
    int cnt = (int)__popcll(mask);
    if (pass) {
      int pos = (int)__popcll(mask & ((1ull << lane) - 1ull));
      s_list[pos] = lane;
    }
    if (cnt == 0) {
#pragma unroll
      for (int c = 0; c < 8; ++c) out[c*Rtot + r] = 0.0f;
      return;
    }

    // zero the step accumulator (own column only)
    for (int i = 0; i < NSTEPS; ++i) acc[i][lane] = 0ull;

    for (int j = 0; j < cnt; ++j) {
      int k = __builtin_amdgcn_readfirstlane(s_list[j]);
      const float* pk = pd + (k << 4);
      float relx = ox - pk[0], rely = oy - pk[1], relz = oz - pk[2];
      float a0 = relx*pk[6] + rely*pk[9]  + relz*pk[12];
      float a1 = relx*pk[7] + rely*pk[10] + relz*pk[13];
      float a2 = relx*pk[8] + rely*pk[11] + relz*pk[14];
      float b0 = dx*pk[6] + dy*pk[9]  + dz*pk[12];
      float b1 = dx*pk[7] + dy*pk[10] + dz*pk[13];
      float b2 = dx*pk[8] + dy*pk[11] + dz*pk[14];
      // inside t-interval: intersection of 3 slabs with the step window
      float tlo = tmin, thi = tmin + (float)NSTEPS*DTc;
#pragma unroll
      for (int ax = 0; ax < 3; ++ax) {
        float aa = (ax == 0) ? a0 : ((ax == 1) ? a1 : a2);
        float bb = (ax == 0) ? b0 : ((ax == 1) ? b1 : b2);
        float inv = 1.0f / bb;
        float q1 = (-1.0f - aa)*inv, q2 = (1.0f - aa)*inv;
        float lo2 = fminf(q1, q2), hi2 = fmaxf(q1, q2);
        if (fabsf(bb) < 1e-7f) {            // degenerate slab
          bool in = fabsf(aa) < 1.0f;
          lo2 = in ? -1e30f : 1e30f;
          hi2 = in ?  1e30f : -1e30f;
        }
        tlo = fmaxf(tlo, lo2);
        thi = fminf(thi, hi2);
      }
      int i0 = (int)ceilf((tlo - tmin)/DTc - 0.5f) - 1;
      int i1 = (int)floorf((thi - tmin)/DTc - 0.5f) + 1;
      i0 = i0 < 0 ? 0 : i0;
      i1 = i1 > NSTEPS-1 ? NSTEPS-1 : i1;
      for (int i = i0; i <= i1; ++i) {
        float t = tmin + ((float)i + 0.5f)*DTc;
        float lx = fmaf(t, b0, a0);
        float ly = fmaf(t, b1, a1);
        float lz = fmaf(t, b2, a2);
        if (fabsf(lx) < 1.0f && fabsf(ly) < 1.0f && fabsf(lz) < 1.0f) {
          float gx = fminf(fmaxf((lx + 1.0f)*7.5f, 0.0f), 14.99999f);
          float gy = fminf(fmaxf((ly + 1.0f)*7.5f, 0.0f), 14.99999f);
          float gz = fminf(fmaxf((lz + 1.0f)*7.5f, 0.0f), 14.99999f);
          int ix = (int)gx, iy = (int)gy, iz = (int)gz;
          float fx = gx - (float)ix, fy = gy - (float)iy, fz = gz - (float)iz;
          int idx = (k << 12) + iz*256 + iy*16 + ix;
          unsigned long long v00 = tv[idx],       v01 = tv[idx + 1];
          unsigned long long v10 = tv[idx + 16],  v11 = tv[idx + 17];
          unsigned long long v20 = tv[idx + 256], v21 = tv[idx + 257];
          unsigned long long v30 = tv[idx + 272], v31 = tv[idx + 273];
          float wx0 = 1.0f - fx;
          float wy0 = 1.0f - fy, wz0 = 1.0f - fz;
          float w00 = wz0*wy0, w01 = wz0*fy, w10 = fz*wy0, w11 = fz*fy;
          float c0 = 0.f, c1 = 0.f, c2 = 0.f, c3 = 0.f;
#define CORNER(va, vb, wc) {                                                  \
          unsigned int alo = (unsigned int)(va), ahi = (unsigned int)((va) >> 32); \
          unsigned int blo = (unsigned int)(vb), bhi = (unsigned int)((vb) >> 32); \
          float2 af01 = __half22float2(*(__half2*)&alo);                      \
          float2 af23 = __half22float2(*(__half2*)&ahi);                      \
          float2 bf01 = __half22float2(*(__half2*)&blo);                      \
          float2 bf23 = __half22float2(*(__half2*)&bhi);                      \
          float wa = (wc)*wx0, wb = (wc)*fx;                                  \
          c0 = fmaf(af01.x, wa, fmaf(bf01.x, wb, c0));                        \
          c1 = fmaf(af01.y, wa, fmaf(bf01.y, wb, c1));                        \
          c2 = fmaf(af23.x, wa, fmaf(bf23.x, wb, c2));                        \
          c3 = fmaf(af23.y, wa, fmaf(bf23.y, wb, c3)); }
          CORNER(v00, v01, w00)
          CORNER(v10, v11, w01)
          CORNER(v20, v21, w10)
          CORNER(v30, v31, w11)
#undef CORNER
          // fp16x4 accumulate into own LDS column (no cross-lane hazard)
          unsigned long long old = acc[i][lane];
          unsigned int olo = (unsigned int)old, ohi = (unsigned int)(old >> 32);
          float2 s01 = __half22float2(*(__half2*)&olo);
          float2 s23 = __half22float2(*(__half2*)&ohi);
          unsigned long long nlo = pack2(s01.x + c0, s01.y + c1);
          unsigned long long nhi = pack2(s23.x + c2, s23.y + c3);
          acc[i][lane] = nlo | (nhi << 32);
        }
      }
    }

    // composite (sequential over steps, matches reference semantics)
    float rgb0 = 0.f, rgb1 = 0.f, rgb2 = 0.f, alpha = 0.f;
    for (int i = 0; i < NSTEPS; ++i) {
      unsigned long long pk2 = acc[i][lane];
      unsigned int lo = (unsigned int)pk2, hi = (unsigned int)(pk2 >> 32);
      float2 lf = __half22float2(*(__half2*)&lo);
      float2 hf = __half22float2(*(__half2*)&hi);
      float t = tmin + ((float)i + 0.5f)*DTc;
      float contrib = fminf(1.0f, fmaf(hf.y, DTc, alpha)) - alpha;
      contrib = (t < tmax) ? contrib : 0.0f;
      rgb0 = fmaf(lf.x, contrib, rgb0);
      rgb1 = fmaf(lf.y, contrib, rgb1);
      rgb2 = fmaf(hf.x, contrib, rgb2);
      alpha += contrib;
    }
    out[0*Rtot + r] = rgb0;
    out[1*Rtot + r] = rgb1;
    out[2*Rtot + r] = rgb2;
    out[3*Rtot + r] = alpha;
    out[4*Rtot + r] = rgb0;
    out[5*Rtot + r] = rgb1;
    out[6*Rtot + r] = rgb2;
    out[7*Rtot + r] = alpha;
  }
}

// Self-contained fallback (no workspace): one thread per ray, all prims.
__global__ __launch_bounds__(256) void fallback_kernel(
    const float* __restrict__ raypos, const float* __restrict__ raydir,
    const float* __restrict__ tminmax,
    const float* __restrict__ primpos, const float* __restrict__ primrot,
    const float* __restrict__ primscale, const float* __restrict__ tmpl,
    float* __restrict__ out) {
  __shared__ float s_pd[Kp][16];
  int tx = threadIdx.x, ty = threadIdx.y;
  int tid = ty*16 + tx;
  if (tid < Kp) {
    int k = tid;
    float sc0 = primscale[k*3+0], sc1 = primscale[k*3+1], sc2 = primscale[k*3+2];
    s_pd[k][0] = primpos[k*3+0]*INV_VOLR;
    s_pd[k][1] = primpos[k*3+1]*INV_VOLR;
    s_pd[k][2] = primpos[k*3+2]*INV_VOLR;
#pragma unroll
    for (int i = 0; i < 3; ++i) {
      s_pd[k][6+i*3+0] = primrot[k*9+i*3+0]*sc0;
      s_pd[k][6+i*3+1] = primrot[k*9+i*3+1]*sc1;
      s_pd[k][6+i*3+2] = primrot[k*9+i*3+2]*sc2;
    }
  }
  __syncthreads();
  int w = blockIdx.x*16 + tx, h = blockIdx.y*16 + ty;
  int r = h*Wimg + w;
  float ox = raypos[r*3+0], oy = raypos[r*3+1], oz = raypos[r*3+2];
  float dx = raydir[r*3+0], dy = raydir[r*3+1], dz = raydir[r*3+2];
  float tmin = tminmax[r*2+0], tmax = tminmax[r*2+1];
  float rgb0=0.f, rgb1=0.f, rgb2=0.f, alpha=0.f;
  for (int i = 0; i < NSTEPS; ++i) {
    float t = tmin + ((float)i + 0.5f)*DTc;
    float px = fmaf(t, dx, ox), py = fmaf(t, dy, oy), pz = fmaf(t, dz, oz);
    float c[4] = {0.f, 0.f, 0.f, 0.f};
    for (int k = 0; k < Kp; ++k) {
      const float* p = &s_pd[k][0];
      float relx = px - p[0], rely = py - p[1], relz = pz - p[2];
      float lx = relx*p[6] + rely*p[9]  + relz*p[12];
      float ly = relx*p[7] + rely*p[10] + relz*p[13];
      float lz = relx*p[8] + rely*p[11] + relz*p[14];
      if (!(fabsf(lx) < 1.0f && fabsf(ly) < 1.0f && fabsf(lz) < 1.0f)) continue;
      float gx = fminf(fmaxf((lx + 1.0f)*7.5f, 0.0f), 14.99999f);
      float gy = fminf(fmaxf((ly + 1.0f)*7.5f, 0.0f), 14.99999f);
      float gz = fminf(fmaxf((lz + 1.0f)*7.5f, 0.0f), 14.99999f);
      int ix = (int)gx, iy = (int)gy, iz = (int)gz;
      ix = ix > 14 ? 14 : ix; iy = iy > 14 ? 14 : iy; iz = iz > 14 ? 14 : iz;
      float fx = gx - (float)ix, fy = gy - (float)iy, fz = gz - (float)iz;
      float wx0 = 1.0f - fx, wy0 = 1.0f - fy, wz0 = 1.0f - fz;
      float w00 = wz0*wy0, w01 = wz0*fy, w10 = fz*wy0, w11 = fz*fy;
      const float* base = tmpl + (((size_t)k) << 14) + iz*256 + iy*16 + ix;
#pragma unroll
      for (int ch = 0; ch < 4; ++ch) {
        const float* bb = base + ch*4096;
        c[ch] += (bb[0]  *wx0 + bb[1]  *fx) * w00
               + (bb[16] *wx0 + bb[17] *fx) * w01
               + (bb[256]*wx0 + bb[257]*fx) * w10
               + (bb[272]*wx0 + bb[273]*fx) * w11;
      }
    }
    float contrib = fminf(1.0f, fmaf(c[3], DTc, alpha)) - alpha;
    contrib = (t < tmax) ? contrib : 0.0f;
    rgb0 = fmaf(c[0], contrib, rgb0);
    rgb1 = fmaf(c[1], contrib, rgb1);
    rgb2 = fmaf(c[2], contrib, rgb2);
    alpha += contrib;
  }
  out[0*Rtot + r] = rgb0;
  out[1*Rtot + r] = rgb1;
  out[2*Rtot + r] = rgb2;
  out[3*Rtot + r] = alpha;
  out[4*Rtot + r] = rgb0;
  out[5*Rtot + r] = rgb1;
  out[6*Rtot + r] = rgb2;
  out[7*Rtot + r] = alpha;
}

extern "C" void kernel_launch(void* const* d_in, const int* in_sizes, int n_in,
                              void* d_out, int out_size, void* d_ws, size_t ws_size,
                              hipStream_t stream) {
  const float* raypos    = (const float*)d_in[0];
  const float* raydir    = (const float*)d_in[1];
  const float* tminmax   = (const float*)d_in[2];
  const float* primpos   = (const float*)d_in[3];
  const float* primrot   = (const float*)d_in[4];
  const float* primscale = (const float*)d_in[5];
  const float* primrgba  = (const float*)d_in[6];
  float* out = (float*)d_out;

  if (ws_size >= WS_NEED) {
    char* ws = (char*)d_ws;
    float* pd = (float*)(ws + PD_OFF);
    unsigned long long* tth = (unsigned long long*)(ws + TT_OFF);

    setup_kernel<<<Kp + 1, 256, 0, stream>>>(primpos, primrot, primscale,
                                             primrgba, tth, pd);
    march_kernel<<<1024, 64, 0, stream>>>(raypos, raydir, tminmax, pd, tth, out);
  } else {
    fallback_kernel<<<dim3(16,16), dim3(16,16), 0, stream>>>(
        raypos, raydir, tminmax, primpos, primrot, primscale, primrgba, out);
  }
}

// Round 11
// 67.515 us; speedup vs baseline: 12.5957x; 12.5957x over previous
//
#include <hip/hip_runtime.h>
#include <hip/hip_fp16.h>

#define Rtot 65536
#define Wimg 256
#define Kp 64
#define NSTEPS 64
#define DTc (1.0f/256.0f)
#define INV_VOLR (1.0f/256.0f)
#define NITEMS 16384

// ws layout (bytes)
#define PD_OFF    0u          // 64 prims * 16 floats = 4 KB
#define TB_OFF    4096u       // 256 tiles * 16 floats = 16 KB
#define FLAG_OFF  20480u      // 16384 B
#define TT_OFF    65536u      // fp16 packed template: 64*4096*16 B = 4 MB
#define SBUF_OFF  8388608u    // fp16 s-buffer: 16384*256*8 B = 33.5 MB
#define WS_NEED   (SBUF_OFF + (size_t)NITEMS*256*8)

typedef _Float16 half2v __attribute__((ext_vector_type(2)));

__device__ __forceinline__ half2v u2h(unsigned int u) {
  union { unsigned int u; half2v h; } x; x.u = u; return x.h;
}
__device__ __forceinline__ half2v mkh2(float a, float b) {
  half2v h; h.x = (_Float16)a; h.y = (_Float16)b; return h;
}
__device__ __forceinline__ unsigned int pack2(float a, float b) {
  __half2 h = __floats2half2_rn(a, b);
  return *(unsigned int*)&h;
}

#if __has_builtin(__builtin_amdgcn_fdot2)
#define FDOT2(a, b, c) __builtin_amdgcn_fdot2((a), (b), (c), false)
#else
#define FDOT2(a, b, c) ((float)(a).x*(float)(b).x + (float)(a).y*(float)(b).y + (c))
#endif

// Fused setup:
//  blocks 0..255   : per-tile bounds of ray origin/dir/tmin -> tb
//  blocks 256..511 : repack template (K,4,16,16,16) f32 -> (K,4096) uint4;
//                    word i = half2(ch_i @ x, ch_i @ x+1)  (x+1 clamped)
//  block 512       : prim data (pos_n, rsc[i][j]=rot[i][j]*scale[j])
__global__ __launch_bounds__(256) void setup_kernel(
    const float* __restrict__ raypos, const float* __restrict__ raydir,
    const float* __restrict__ tminmax, const float* __restrict__ primpos,
    const float* __restrict__ primrot, const float* __restrict__ primscale,
    const float* __restrict__ tmpl,
    float* __restrict__ tb, uint4* __restrict__ tth, float* __restrict__ pd) {
  int bid = blockIdx.x, tid = threadIdx.x;
  if (bid < 256) {
    __shared__ float smn[4][7], smx[4][7];
    int w = (bid & 15)*16 + (tid & 15);
    int h = (bid >> 4)*16 + (tid >> 4);
    int r = h*Wimg + w;
    float v[7];
    v[0] = raypos[r*3+0]; v[1] = raypos[r*3+1]; v[2] = raypos[r*3+2];
    v[3] = raydir[r*3+0]; v[4] = raydir[r*3+1]; v[5] = raydir[r*3+2];
    v[6] = tminmax[r*2+0];
    float mn[7], mx[7];
#pragma unroll
    for (int i = 0; i < 7; ++i) { mn[i] = v[i]; mx[i] = v[i]; }
#pragma unroll
    for (int m = 1; m < 64; m <<= 1) {
#pragma unroll
      for (int i = 0; i < 7; ++i) {
        mn[i] = fminf(mn[i], __shfl_xor(mn[i], m));
        mx[i] = fmaxf(mx[i], __shfl_xor(mx[i], m));
      }
    }
    int wv = tid >> 6;
    if ((tid & 63) == 0) {
#pragma unroll
      for (int i = 0; i < 7; ++i) { smn[wv][i] = mn[i]; smx[wv][i] = mx[i]; }
    }
    __syncthreads();
    if (tid == 0) {
#pragma unroll
      for (int i = 0; i < 7; ++i) {
        tb[bid*16 + i]     = fminf(fminf(smn[0][i], smn[1][i]), fminf(smn[2][i], smn[3][i]));
        tb[bid*16 + 8 + i] = fmaxf(fmaxf(smx[0][i], smx[1][i]), fmaxf(smx[2][i], smx[3][i]));
      }
    }
  } else if (bid < 512) {
    int k = (bid - 256) >> 2;
    int q = (bid - 256) & 3;
    const float* b0 = tmpl + (((size_t)k) << 14);
    uint4* o = tth + (k << 12);
#pragma unroll
    for (int s = 0; s < 4; ++s) {
      int v = q*1024 + s*256 + tid;
      int x = v & 15;
      int xn = (x < 15) ? v + 1 : v;
      uint4 qq;
      qq.x = pack2(b0[v],       b0[xn]);
      qq.y = pack2(b0[4096+v],  b0[4096+xn]);
      qq.z = pack2(b0[8192+v],  b0[8192+xn]);
      qq.w = pack2(b0[12288+v], b0[12288+xn]);
      o[v] = qq;
    }
  } else {
    int k = tid;
    if (k < Kp) {
      float sc0 = primscale[k*3+0], sc1 = primscale[k*3+1], sc2 = primscale[k*3+2];
      float* o = pd + (k << 4);
      o[0] = primpos[k*3+0] * INV_VOLR;
      o[1] = primpos[k*3+1] * INV_VOLR;
      o[2] = primpos[k*3+2] * INV_VOLR;
      o[3] = 0.0f; o[4] = 0.0f; o[5] = 0.0f;
#pragma unroll
      for (int i = 0; i < 3; ++i) {
        o[6+i*3+0] = primrot[k*9+i*3+0]*sc0;
        o[6+i*3+1] = primrot[k*9+i*3+1]*sc1;
        o[6+i*3+2] = primrot[k*9+i*3+2]*sc2;
      }
      o[15] = 0.0f;
    }
  }
}

// Shade: one block per (tile,step). Wave 0 culls prims (tile-interval test in
// prim-local space); every block writes its flag; empties exit; survivors
// shade 256 rays with a simple gated prim loop (wave-skip + per-lane gate)
// and fdot2 trilinear on the 16B/voxel packed table.
__global__ __launch_bounds__(256) void shade_kernel(
    const float* __restrict__ raypos, const float* __restrict__ raydir,
    const float* __restrict__ tminmax, const float* __restrict__ pd,
    const float* __restrict__ tb, const uint4* __restrict__ tth,
    unsigned long long* __restrict__ sbuf, unsigned char* __restrict__ flags) {
  __shared__ int s_list[Kp];
  __shared__ int s_cnt;
  int item = blockIdx.x;
  int tile = item >> 6, step = item & 63;
  int tid = threadIdx.x;
  if (tid < 64) {
    const float* t0 = tb + tile*16;
    float cst = ((float)step + 0.5f)*DTc;
    float tl = t0[6] + cst, th = t0[14] + cst;
    const float* p = pd + (tid << 4);
    float rlo[3], rhi[3];
#pragma unroll
    for (int a = 0; a < 3; ++a) {
      float ol = t0[a], oh = t0[8+a], dl = t0[3+a], dh = t0[11+a];
      float p1 = tl*dl, p2 = tl*dh, p3 = th*dl, p4 = th*dh;
      rlo[a] = ol + fminf(fminf(p1, p2), fminf(p3, p4)) - p[a];
      rhi[a] = oh + fmaxf(fmaxf(p1, p2), fmaxf(p3, p4)) - p[a];
    }
    bool pass = true;
#pragma unroll
    for (int j = 0; j < 3; ++j) {
      float llo = 0.f, lhi = 0.f;
#pragma unroll
      for (int a = 0; a < 3; ++a) {
        float rsc = p[6+a*3+j];
        float q1 = rlo[a]*rsc, q2 = rhi[a]*rsc;
        llo += fminf(q1, q2);
        lhi += fmaxf(q1, q2);
      }
      pass = pass && (llo < 1.0f) && (lhi > -1.0f);
    }
    unsigned long long mask = __ballot(pass);
    if (tid == 0) s_cnt = (int)__popcll(mask);
    if (pass) {
      int pos = (int)__popcll(mask & ((1ull << tid) - 1ull));
      s_list[pos] = tid;
    }
  }
  __syncthreads();
  int cnt = s_cnt;
  if (tid == 0) flags[item] = (unsigned char)(cnt > 0 ? 1 : 0);
  if (cnt == 0) return;

  int w = (tile & 15)*16 + (tid & 15);
  int h = (tile >> 4)*16 + (tid >> 4);
  int r = h*Wimg + w;
  float t = tminmax[r*2] + ((float)step + 0.5f)*DTc;
  float px = fmaf(t, raydir[r*3+0], raypos[r*3+0]);
  float py = fmaf(t, raydir[r*3+1], raypos[r*3+1]);
  float pz = fmaf(t, raydir[r*3+2], raypos[r*3+2]);
  float c0 = 0.f, c1 = 0.f, c2 = 0.f, c3 = 0.f;

  for (int j = 0; j < cnt; ++j) {
    int k = __builtin_amdgcn_readfirstlane(s_list[j]);
    const float* p = pd + (k << 4);
    float relx = px - p[0], rely = py - p[1], relz = pz - p[2];
    float lx = relx*p[6] + rely*p[9]  + relz*p[12];
    float ly = relx*p[7] + rely*p[10] + relz*p[13];
    float lz = relx*p[8] + rely*p[11] + relz*p[14];
    bool inside = fabsf(lx) < 1.0f && fabsf(ly) < 1.0f && fabsf(lz) < 1.0f;
    if (!__any(inside)) continue;
    if (inside) {
      float gx = fminf(fmaxf((lx + 1.0f)*7.5f, 0.0f), 14.99999f);
      float gy = fminf(fmaxf((ly + 1.0f)*7.5f, 0.0f), 14.99999f);
      float gz = fminf(fmaxf((lz + 1.0f)*7.5f, 0.0f), 14.99999f);
      int ix = (int)gx, iy = (int)gy, iz = (int)gz;
      float fx = gx - (float)ix, fy = gy - (float)iy, fz = gz - (float)iz;
      float wx0 = 1.0f - fx;
      float wy0 = 1.0f - fy, wz0 = 1.0f - fz;
      float w00 = wz0*wy0, w01 = wz0*fy, w10 = fz*wy0, w11 = fz*fy;
      const uint4* a = tth + ((size_t)k << 12) + (iz*256 + iy*16 + ix);
      uint4 q0 = a[0], q1 = a[16], q2 = a[256], q3 = a[272];
      half2v wp0 = mkh2(w00*wx0, w00*fx);
      half2v wp1 = mkh2(w01*wx0, w01*fx);
      half2v wp2 = mkh2(w10*wx0, w10*fx);
      half2v wp3 = mkh2(w11*wx0, w11*fx);
      c0 = FDOT2(u2h(q0.x), wp0, c0);
      c1 = FDOT2(u2h(q0.y), wp0, c1);
      c2 = FDOT2(u2h(q0.z), wp0, c2);
      c3 = FDOT2(u2h(q0.w), wp0, c3);
      c0 = FDOT2(u2h(q1.x), wp1, c0);
      c1 = FDOT2(u2h(q1.y), wp1, c1);
      c2 = FDOT2(u2h(q1.z), wp1, c2);
      c3 = FDOT2(u2h(q1.w), wp1, c3);
      c0 = FDOT2(u2h(q2.x), wp2, c0);
      c1 = FDOT2(u2h(q2.y), wp2, c1);
      c2 = FDOT2(u2h(q2.z), wp2, c2);
      c3 = FDOT2(u2h(q2.w), wp2, c3);
      c0 = FDOT2(u2h(q3.x), wp3, c0);
      c1 = FDOT2(u2h(q3.y), wp3, c1);
      c2 = FDOT2(u2h(q3.z), wp3, c2);
      c3 = FDOT2(u2h(q3.w), wp3, c3);
    }
  }
  unsigned long long pk = ((unsigned long long)pack2(c2, c3) << 32)
                        | (unsigned long long)pack2(c0, c1);
  sbuf[item*256 + tid] = pk;
}

// Composite: one thread per ray; flag-gated sbuf loads (uniform branch).
__global__ __launch_bounds__(256) void composite_kernel(
    const float* __restrict__ tminmax, const unsigned long long* __restrict__ sbuf,
    const unsigned char* __restrict__ flags, float* __restrict__ out) {
  __shared__ unsigned char s_flags[NSTEPS];
  int tid = threadIdx.x;
  int b = blockIdx.x;
  if (tid < NSTEPS) s_flags[tid] = flags[b*NSTEPS + tid];
  __syncthreads();
  int w = (b & 15)*16 + (tid & 15);
  int h = (b >> 4)*16 + (tid >> 4);
  int r = h*Wimg + w;
  float tmin = tminmax[r*2+0], tmax = tminmax[r*2+1];
  float rgb0 = 0.f, rgb1 = 0.f, rgb2 = 0.f, alpha = 0.f;
  for (int i = 0; i < NSTEPS; ++i) {
    float s0 = 0.f, s1 = 0.f, s2 = 0.f, s3 = 0.f;
    if (s_flags[i]) {
      unsigned long long pk = sbuf[(b*NSTEPS + i)*256 + tid];
      unsigned int lo = (unsigned int)pk, hi = (unsigned int)(pk >> 32);
      float2 lf = __half22float2(*(__half2*)&lo);
      float2 hf = __half22float2(*(__half2*)&hi);
      s0 = lf.x; s1 = lf.y; s2 = hf.x; s3 = hf.y;
    }
    float t = tmin + ((float)i + 0.5f)*DTc;
    float contrib = fminf(1.0f, fmaf(s3, DTc, alpha)) - alpha;
    contrib = (t < tmax) ? contrib : 0.0f;
    rgb0 = fmaf(s0, contrib, rgb0);
    rgb1 = fmaf(s1, contrib, rgb1);
    rgb2 = fmaf(s2, contrib, rgb2);
    alpha += contrib;
  }
  out[0*Rtot + r] = rgb0;
  out[1*Rtot + r] = rgb1;
  out[2*Rtot + r] = rgb2;
  out[3*Rtot + r] = alpha;
  out[4*Rtot + r] = rgb0;
  out[5*Rtot + r] = rgb1;
  out[6*Rtot + r] = rgb2;
  out[7*Rtot + r] = alpha;
}

// Self-contained fallback (no workspace): one thread per ray, all prims.
__global__ __launch_bounds__(256) void fallback_kernel(
    const float* __restrict__ raypos, const float* __restrict__ raydir,
    const float* __restrict__ tminmax,
    const float* __restrict__ primpos, const float* __restrict__ primrot,
    const float* __restrict__ primscale, const float* __restrict__ tmpl,
    float* __restrict__ out) {
  __shared__ float s_pd[Kp][16];
  int tx = threadIdx.x, ty = threadIdx.y;
  int tid = ty*16 + tx;
  if (tid < Kp) {
    int k = tid;
    float sc0 = primscale[k*3+0], sc1 = primscale[k*3+1], sc2 = primscale[k*3+2];
    s_pd[k][0] = primpos[k*3+0]*INV_VOLR;
    s_pd[k][1] = primpos[k*3+1]*INV_VOLR;
    s_pd[k][2] = primpos[k*3+2]*INV_VOLR;
#pragma unroll
    for (int i = 0; i < 3; ++i) {
      s_pd[k][6+i*3+0] = primrot[k*9+i*3+0]*sc0;
      s_pd[k][6+i*3+1] = primrot[k*9+i*3+1]*sc1;
      s_pd[k][6+i*3+2] = primrot[k*9+i*3+2]*sc2;
    }
  }
  __syncthreads();
  int w = blockIdx.x*16 + tx, h = blockIdx.y*16 + ty;
  int r = h*Wimg + w;
  float ox = raypos[r*3+0], oy = raypos[r*3+1], oz = raypos[r*3+2];
  float dx = raydir[r*3+0], dy = raydir[r*3+1], dz = raydir[r*3+2];
  float tmin = tminmax[r*2+0], tmax = tminmax[r*2+1];
  float rgb0=0.f, rgb1=0.f, rgb2=0.f, alpha=0.f;
  for (int i = 0; i < NSTEPS; ++i) {
    float t = tmin + ((float)i + 0.5f)*DTc;
    float px = fmaf(t, dx, ox), py = fmaf(t, dy, oy), pz = fmaf(t, dz, oz);
    float c[4] = {0.f, 0.f, 0.f, 0.f};
    for (int k = 0; k < Kp; ++k) {
      const float* p = &s_pd[k][0];
      float relx = px - p[0], rely = py - p[1], relz = pz - p[2];
      float lx = relx*p[6] + rely*p[9]  + relz*p[12];
      float ly = relx*p[7] + rely*p[10] + relz*p[13];
      float lz = relx*p[8] + rely*p[11] + relz*p[14];
      if (!(fabsf(lx) < 1.0f && fabsf(ly) < 1.0f && fabsf(lz) < 1.0f)) continue;
      float gx = fminf(fmaxf((lx + 1.0f)*7.5f, 0.0f), 14.99999f);
      float gy = fminf(fmaxf((ly + 1.0f)*7.5f, 0.0f), 14.99999f);
      float gz = fminf(fmaxf((lz + 1.0f)*7.5f, 0.0f), 14.99999f);
      int ix = (int)gx, iy = (int)gy, iz = (int)gz;
      ix = ix > 14 ? 14 : ix; iy = iy > 14 ? 14 : iy; iz = iz > 14 ? 14 : iz;
      float fx = gx - (float)ix, fy = gy - (float)iy, fz = gz - (float)iz;
      float wx0 = 1.0f - fx, wy0 = 1.0f - fy, wz0 = 1.0f - fz;
      float w00 = wz0*wy0, w01 = wz0*fy, w10 = fz*wy0, w11 = fz*fy;
      const float* base = tmpl + (((size_t)k) << 14) + iz*256 + iy*16 + ix;
#pragma unroll
      for (int ch = 0; ch < 4; ++ch) {
        const float* bb = base + ch*4096;
        c[ch] += (bb[0]  *wx0 + bb[1]  *fx) * w00
               + (bb[16] *wx0 + bb[17] *fx) * w01
               + (bb[256]*wx0 + bb[257]*fx) * w10
               + (bb[272]*wx0 + bb[273]*fx) * w11;
      }
    }
    float contrib = fminf(1.0f, fmaf(c[3], DTc, alpha)) - alpha;
    contrib = (t < tmax) ? contrib : 0.0f;
    rgb0 = fmaf(c[0], contrib, rgb0);
    rgb1 = fmaf(c[1], contrib, rgb1);
    rgb2 = fmaf(c[2], contrib, rgb2);
    alpha += contrib;
  }
  out[0*Rtot + r] = rgb0;
  out[1*Rtot + r] = rgb1;
  out[2*Rtot + r] = rgb2;
  out[3*Rtot + r] = alpha;
  out[4*Rtot + r] = rgb0;
  out[5*Rtot + r] = rgb1;
  out[6*Rtot + r] = rgb2;
  out[7*Rtot + r] = alpha;
}

extern "C" void kernel_launch(void* const* d_in, const int* in_sizes, int n_in,
                              void* d_out, int out_size, void* d_ws, size_t ws_size,
                              hipStream_t stream) {
  const float* raypos    = (const float*)d_in[0];
  const float* raydir    = (const float*)d_in[1];
  const float* tminmax   = (const float*)d_in[2];
  const float* primpos   = (const float*)d_in[3];
  const float* primrot   = (const float*)d_in[4];
  const float* primscale = (const float*)d_in[5];
  const float* primrgba  = (const float*)d_in[6];
  float* out = (float*)d_out;

  if (ws_size >= WS_NEED) {
    char* ws = (char*)d_ws;
    float* pd            = (float*)(ws + PD_OFF);
    float* tb            = (float*)(ws + TB_OFF);
    unsigned char* flags = (unsigned char*)(ws + FLAG_OFF);
    uint4* tth           = (uint4*)(ws + TT_OFF);
    unsigned long long* sbuf = (unsigned long long*)(ws + SBUF_OFF);

    setup_kernel<<<513, 256, 0, stream>>>(raypos, raydir, tminmax, primpos,
                                          primrot, primscale, primrgba,
                                          tb, tth, pd);
    shade_kernel<<<NITEMS, 256, 0, stream>>>(raypos, raydir, tminmax, pd, tb,
                                             tth, sbuf, flags);
    composite_kernel<<<256, 256, 0, stream>>>(tminmax, sbuf, flags, out);
  } else {
    fallback_kernel<<<dim3(16,16), dim3(16,16), 0, stream>>>(
        raypos, raydir, tminmax, primpos, primrot, primscale, primrgba, out);
  }
}